// Round 15
// baseline (137.889 us; speedup 1.0000x reference)
//
#include <hip/hip_runtime.h>
#include <stdint.h>

typedef __attribute__((ext_vector_type(4))) float f32x4;
typedef __attribute__((ext_vector_type(8))) __bf16 bf16x8;
typedef __attribute__((ext_vector_type(8))) unsigned short u16x8;

__device__ __forceinline__ unsigned short f2b(float f) {
  unsigned u = __float_as_uint(f);
  u += 0x7FFFu + ((u >> 16) & 1u);   // RNE
  return (unsigned short)(u >> 16);
}
__device__ __forceinline__ float b2f(unsigned short s) {
  unsigned u = (unsigned)s << 16;
  return __uint_as_float(u);
}
__device__ __forceinline__ unsigned cvtpk_bf16(float lo, float hi) {
  unsigned r;
  asm("v_cvt_pk_bf16_f32 %0, %1, %2" : "=v"(r) : "v"(lo), "v"(hi));
  return r;
}

__device__ __forceinline__ void gload_lds16(const void* g, void* l) {
  typedef __attribute__((address_space(1))) void GV1;
  typedef __attribute__((address_space(3))) void LV3;
  __builtin_amdgcn_global_load_lds((GV1*)(void*)g, (LV3*)l, 16, 0, 0);
}

// counted-vmcnt tile barrier (T4): wait own oldest loads, keep newest N flying,
// then s_barrier. sched_barrier(0) fences against compiler hoisting (rule #18).
__device__ __forceinline__ void tile_barrier_keep2() {
  asm volatile("s_waitcnt vmcnt(2)" ::: "memory");
  __builtin_amdgcn_sched_barrier(0);
  __builtin_amdgcn_s_barrier();
  __builtin_amdgcn_sched_barrier(0);
}
__device__ __forceinline__ void tile_barrier_keep0() {
  asm volatile("s_waitcnt vmcnt(0)" ::: "memory");
  __builtin_amdgcn_sched_barrier(0);
  __builtin_amdgcn_s_barrier();
  __builtin_amdgcn_sched_barrier(0);
}

// ---------------- conversion kernels ----------------
__global__ __launch_bounds__(256) void convert_f32_bf16(const float* __restrict__ in,
                                                        unsigned short* __restrict__ out, int n) {
  int i = (blockIdx.x * 256 + threadIdx.x) * 8;
  if (i >= n) return;
  float4 a = *(const float4*)(in + i);
  float4 b = *(const float4*)(in + i + 4);
  u16x8 r;
  r[0] = f2b(a.x); r[1] = f2b(a.y); r[2] = f2b(a.z); r[3] = f2b(a.w);
  r[4] = f2b(b.x); r[5] = f2b(b.y); r[6] = f2b(b.z); r[7] = f2b(b.w);
  *(u16x8*)(out + i) = r;
}

// W [K][N] f32 -> Wt [N][K] bf16
__global__ __launch_bounds__(256) void transpose_f32_bf16(const float* __restrict__ W,
                                                          unsigned short* __restrict__ Wt,
                                                          int K, int N) {
  __shared__ unsigned short tile[32][33];
  int n0 = blockIdx.x * 32, k0 = blockIdx.y * 32;
  int tx = threadIdx.x, ty = threadIdx.y;  // 32 x 8
  #pragma unroll
  for (int j = 0; j < 32; j += 8)
    tile[ty + j][tx] = f2b(W[(size_t)(k0 + ty + j) * N + n0 + tx]);
  __syncthreads();
  #pragma unroll
  for (int j = 0; j < 32; j += 8)
    Wt[(size_t)(n0 + ty + j) * K + k0 + tx] = tile[tx][ty + j];
}

// ---------------- GEMM: C[M][N] = A[M][K] * Bt[N][K]^T + bias ----------------
// (R14 structure, unchanged: 2-phase double-buffer, 8 waves, wave-tile 64x32)
template <bool OUT_BF16, bool VSPLIT>
__global__ __launch_bounds__(512) void gemm_bt(const unsigned short* __restrict__ A,
                                               const unsigned short* __restrict__ Bt,
                                               const float* __restrict__ bias,
                                               void* __restrict__ Cout,
                                               unsigned short* __restrict__ vT,
                                               int M, int N, int K) {
  __shared__ unsigned short SMEM[32768];           // 64KB: [buf][A|B][128*64]
  const int m0 = blockIdx.x * 128, n0 = blockIdx.y * 128;
  const int tid = threadIdx.x;
  const int w = tid >> 6, l = tid & 63;
  const int wm = w >> 2, wn = w & 3;               // 2 x 4 waves, tile 64 x 32
  const int c = l & 15, g = l >> 4;
  const int NT = K >> 6;                           // K-steps (BK=64)
  const unsigned short* aptr[2];
  const unsigned short* bptr[2];
  #pragma unroll
  for (int i = 0; i < 2; ++i) {
    int rb = w * 16 + i * 8;
    aptr[i] = A  + (size_t)(m0 + rb + (l >> 3)) * K + (l & 7) * 8;
    bptr[i] = Bt + (size_t)(n0 + rb + (l >> 3)) * K + (l & 7) * 8;
  }
  f32x4 acc[4][2] = {};
  #pragma unroll
  for (int i = 0; i < 2; ++i) {
    int rb = w * 16 + i * 8;
    gload_lds16(aptr[i], &SMEM[rb * 64]);
    gload_lds16(bptr[i], &SMEM[8192 + rb * 64]);
  }
  __syncthreads();
  for (int t = 0; t < NT; ++t) {
    const int cur = t & 1;
    const unsigned short* Ab = &SMEM[cur * 16384];
    const unsigned short* Bb = &SMEM[cur * 16384 + 8192];
    if (t + 1 < NT) {  // issue next-step loads BEFORE compute (2-phase)
      unsigned short* An = &SMEM[(cur ^ 1) * 16384];
      unsigned short* Bn = &SMEM[(cur ^ 1) * 16384 + 8192];
      #pragma unroll
      for (int i = 0; i < 2; ++i) {
        int rb = w * 16 + i * 8;
        gload_lds16(aptr[i] + (size_t)(t + 1) * 64, &An[rb * 64]);
        gload_lds16(bptr[i] + (size_t)(t + 1) * 64, &Bn[rb * 64]);
      }
    }
    #pragma unroll
    for (int ks = 0; ks < 2; ++ks) {
      bf16x8 af[4], bf[2];
      #pragma unroll
      for (int mi = 0; mi < 4; ++mi)
        af[mi] = *(const bf16x8*)&Ab[(wm * 64 + mi * 16 + c) * 64 + ks * 32 + g * 8];
      #pragma unroll
      for (int ni = 0; ni < 2; ++ni)
        bf[ni] = *(const bf16x8*)&Bb[(wn * 32 + ni * 16 + c) * 64 + ks * 32 + g * 8];
      __builtin_amdgcn_s_setprio(1);
      #pragma unroll
      for (int mi = 0; mi < 4; ++mi)
        #pragma unroll
        for (int ni = 0; ni < 2; ++ni)
          acc[mi][ni] = __builtin_amdgcn_mfma_f32_16x16x32_bf16(af[mi], bf[ni], acc[mi][ni], 0, 0, 0);
      __builtin_amdgcn_s_setprio(0);
    }
    __syncthreads();  // one barrier per step
  }
  if (VSPLIT && n0 >= 2048) {
    unsigned short* TR = SMEM;                     // [128 cols][136]
    #pragma unroll
    for (int mi = 0; mi < 4; ++mi)
      #pragma unroll
      for (int ni = 0; ni < 2; ++ni) {
        int cl = wn * 32 + ni * 16 + c;
        float bv = bias[n0 + cl];
        int rlb = wm * 64 + mi * 16 + 4 * g;
        ushort4 o4;
        o4.x = f2b(acc[mi][ni][0] + bv); o4.y = f2b(acc[mi][ni][1] + bv);
        o4.z = f2b(acc[mi][ni][2] + bv); o4.w = f2b(acc[mi][ni][3] + bv);
        *(ushort4*)&TR[cl * 136 + rlb] = o4;
      }
    __syncthreads();
    const int d0 = n0 - 2048;
    #pragma unroll
    for (int p = 0; p < 4; ++p) {
      int rowl = p * 32 + (tid >> 4);
      *(u16x8*)(vT + (size_t)(d0 + rowl) * 4096 + m0 + (tid & 15) * 8) =
          *(const u16x8*)&TR[rowl * 136 + (tid & 15) * 8];
    }
    return;
  }
  const int NS = VSPLIT ? 2048 : N;
  #pragma unroll
  for (int mi = 0; mi < 4; ++mi) {
    #pragma unroll
    for (int ni = 0; ni < 2; ++ni) {
      int colg = n0 + wn * 32 + ni * 16 + c;
      float bv = bias[colg];
      #pragma unroll
      for (int r = 0; r < 4; ++r) {
        int rowg = m0 + wm * 64 + mi * 16 + 4 * g + r;
        float v = acc[mi][ni][r] + bv;
        if (OUT_BF16)
          ((unsigned short*)Cout)[(size_t)rowg * NS + colg] = f2b(v);
        else
          ((float*)Cout)[(size_t)rowg * NS + colg] = v;
      }
    }
  }
}

// ---------------- causal flash attention, SPLIT-KV + SWAPPED MFMA, QBLK=128 ----
// R14 analysis: ~5800 cy per wave-tile interval vs ~700 cy work — the per-tile
// __syncthreads drains vmcnt(0) (including just-issued next-tile loads) and
// lockstops 8 waves. THIS ROUND (T4 minimal): TRIPLE-buffer K/V (48KB), stage
// tile t+2 each iter (2 compute-phases of latency cover), and replace
// __syncthreads with {s_waitcnt vmcnt(2); s_barrier} — each wave keeps its 2
// newest loads IN FLIGHT across the barrier (never drain to 0 in main loop).
__global__ __launch_bounds__(512) void attn_kernel(const unsigned short* __restrict__ qk,
                                                   const unsigned short* __restrict__ vT,
                                                   unsigned short* __restrict__ partO,
                                                   float* __restrict__ partML) {
  __shared__ unsigned short K_lds[3][64 * 64];     // [buf][kv][d], XOR-swizzled rows
  __shared__ unsigned short V_lds[3][64 * 64];     // [buf] V^T [d][kv], XOR-swizzled rows
  const int bid = blockIdx.x;
  const int bh = bid & 31;
  const int cid = 39 - (bid >> 5);                 // heavy-first
  int qt, ct;
  if (cid < 4)       { qt = cid;            ct = 0; }
  else if (cid < 12) { int e = cid - 4;  qt = 4 + (e >> 1);  ct = e & 1; }
  else if (cid < 24) { int e = cid - 12; int q3 = e / 3; qt = 8 + q3; ct = e - 3 * q3; }
  else               { int e = cid - 24; qt = 12 + (e >> 2); ct = e & 3; }
  const int ntt = 2 * qt + 2;                      // total kv tiles for this q-tile
  const int t0 = ct * 8;
  const int ntl = min(ntt - t0, 8);                // tiles in this chunk (1..8)
  const int b = bh >> 4, h = bh & 15;
  const int tid = threadIdx.x, w = tid >> 6, l = tid & 63;
  const int c = l & 15, g = l >> 4;
  const int hi = g >> 1;
  const int srcA = c + ((g & 1) << 5);             // bpermute pattern A (j=0,1)
  const int srcB = srcA + 16;                      // pattern B (j=2,3)
  const size_t row0 = (size_t)b * 2048;
  const float SCL = 0.18033688f;                   // 0.125 * log2(e)
  const int KSTRIDE = 64 * 2048;                   // qk elems per kv-tile step
  const int VSTRIDE = 64;                          // vT elems per kv-tile step

  const int q0w = qt * 128 + w * 16;
  const int qg = q0w + c;                          // this lane's q row (global)

  // Q fragments (B operand of swapped QK^T) — issued first (oldest in vmcnt)
  bf16x8 qf[2];
  #pragma unroll
  for (int ks = 0; ks < 2; ++ks)
    qf[ks] = *(const bf16x8*)(qk + (row0 + qg) * 2048 + h * 64 + ks * 32 + g * 8);

  f32x4 acc[4] = {};                               // O^T: acc[nd][r] = O[q=c][d=16nd+4g+r]
  float mstate = -1e30f, lstate = 0.f;

  // ---- hoisted per-lane global pointers (advance per tile)
  const int krow = w * 8 + (l >> 3);               // lane's row in tile (K: kv; V: d)
  const int kch = (l & 7) ^ (krow & 7);            // pre-swizzled source chunk (m173)
  const unsigned short* kptr = qk + (row0 + t0 * 64 + krow) * 2048 + 1024 + h * 64 + kch * 8;
  const unsigned short* vptr = vT + (size_t)(h * 64 + krow) * 4096 + (b * 2048 + t0 * 64) + kch * 8;
  const int kdst = (w * 8) * 64;                   // wave-uniform LDS base (elems)

  // ---- prologue: stage t0 -> buf0, t1 -> buf1 (deep prefetch)
  gload_lds16(kptr, &K_lds[0][kdst]);
  gload_lds16(vptr, &V_lds[0][kdst]);
  if (ntl > 1) {
    gload_lds16(kptr + KSTRIDE, &K_lds[1][kdst]);
    gload_lds16(vptr + VSTRIDE, &V_lds[1][kdst]);
    tile_barrier_keep2();                          // Q + t0 done; t1 still flying
  } else {
    tile_barrier_keep0();
  }

  int cur = 0;
  for (int lt = 0; lt < ntl; ++lt) {
    const int kv0 = (t0 + lt) * 64;
    const bool pre2 = (lt + 2 < ntl);
    if (pre2) {  // stage tile t+2 into the buffer freed at the last barrier
      int sb = cur + 2; if (sb >= 3) sb -= 3;
      gload_lds16(kptr + 2 * KSTRIDE, &K_lds[sb][kdst]);
      gload_lds16(vptr + 2 * VSTRIDE, &V_lds[sb][kdst]);
    }
    kptr += KSTRIDE;
    vptr += VSTRIDE;
    if (kv0 <= q0w + 15) {  // wave-uniform: skip tiles fully above the diagonal
      const char* Kb = (const char*)K_lds[cur];
      const char* Vb = (const char*)V_lds[cur];
      // ---- S^T = mfma(K, Q): s[nk][r] = S[q=qg][kv = kv0 + 16nk + 4g + r]
      f32x4 s[4] = {};
      #pragma unroll
      for (int ks = 0; ks < 2; ++ks) {
        bf16x8 kf[4];
        #pragma unroll
        for (int nk = 0; nk < 4; ++nk) {
          int row = nk * 16 + c;
          kf[nk] = *(const bf16x8*)(Kb + row * 128 + ((ks * 64 + g * 16) ^ ((row & 7) << 4)));
        }
        __builtin_amdgcn_s_setprio(1);
        #pragma unroll
        for (int nk = 0; nk < 4; ++nk)
          s[nk] = __builtin_amdgcn_mfma_f32_16x16x32_bf16(kf[nk], qf[ks], s[nk], 0, 0, 0);
        __builtin_amdgcn_s_setprio(0);
      }
      // ---- causal mask on any tile straddling this wave's rows (wave-uniform)
      if (kv0 + 63 > q0w) {
        #pragma unroll
        for (int nk = 0; nk < 4; ++nk)
          #pragma unroll
          for (int r = 0; r < 4; ++r) {
            int kvg = kv0 + nk * 16 + 4 * g + r;
            if (kvg > qg) s[nk][r] = -1e30f;
          }
      }
      // ---- row max: in-lane tree + 2 shfls (lanes c,c+16,c+32,c+48 share q)
      float a0 = fmaxf(fmaxf(s[0][0], s[0][1]), fmaxf(s[0][2], s[0][3]));
      float a1 = fmaxf(fmaxf(s[1][0], s[1][1]), fmaxf(s[1][2], s[1][3]));
      float a2 = fmaxf(fmaxf(s[2][0], s[2][1]), fmaxf(s[2][2], s[2][3]));
      float a3 = fmaxf(fmaxf(s[3][0], s[3][1]), fmaxf(s[3][2], s[3][3]));
      float mx = fmaxf(fmaxf(a0, a1), fmaxf(a2, a3));
      mx = fmaxf(mx, __shfl_xor(mx, 16));
      mx = fmaxf(mx, __shfl_xor(mx, 32));
      // ---- alpha==1 fast path (wave-uniform); rescale lane-local
      if (!__all(mx <= mstate)) {
        float mnew = fmaxf(mstate, mx);
        float alpha = exp2f((mstate - mnew) * SCL);
        mstate = mnew;
        lstate *= alpha;
        #pragma unroll
        for (int nd = 0; nd < 4; ++nd) acc[nd] *= alpha;
      }
      // ---- P = exp2(s*SCL - m*SCL), per-lane l partial
      float ms = mstate * SCL;
      #pragma unroll
      for (int nk = 0; nk < 4; ++nk) {
        #pragma unroll
        for (int r = 0; r < 4; ++r) s[nk][r] = exp2f(fmaf(s[nk][r], SCL, -ms));
        lstate += (s[nk][0] + s[nk][1]) + (s[nk][2] + s[nk][3]);
      }
      // ---- pack P to bf16 pairs
      unsigned pk[4][2];
      #pragma unroll
      for (int nk = 0; nk < 4; ++nk) {
        pk[nk][0] = cvtpk_bf16(s[nk][0], s[nk][1]);
        pk[nk][1] = cvtpk_bf16(s[nk][2], s[nk][3]);
      }
      // ---- O^T += mfma(V^T, P^T): B-frag pa[vks] = P[q=c][kv=32vks+8g+e]
      #pragma unroll
      for (int vks = 0; vks < 2; ++vks) {
        unsigned rA00 = __shfl(pk[2 * vks][0], srcA, 64);
        unsigned rA01 = __shfl(pk[2 * vks][1], srcA, 64);
        unsigned rA10 = __shfl(pk[2 * vks + 1][0], srcA, 64);
        unsigned rA11 = __shfl(pk[2 * vks + 1][1], srcA, 64);
        unsigned rB00 = __shfl(pk[2 * vks][0], srcB, 64);
        unsigned rB01 = __shfl(pk[2 * vks][1], srcB, 64);
        unsigned rB10 = __shfl(pk[2 * vks + 1][0], srcB, 64);
        unsigned rB11 = __shfl(pk[2 * vks + 1][1], srcB, 64);
        union { unsigned u[4]; bf16x8 v; } pa;
        pa.u[0] = hi ? rA10 : rA00;
        pa.u[1] = hi ? rA11 : rA01;
        pa.u[2] = hi ? rB10 : rB00;
        pa.u[3] = hi ? rB11 : rB01;
        bf16x8 vf[4];
        #pragma unroll
        for (int nd = 0; nd < 4; ++nd) {
          int row = nd * 16 + c;
          vf[nd] = *(const bf16x8*)(Vb + row * 128 + ((vks * 64 + g * 16) ^ ((row & 7) << 4)));
        }
        __builtin_amdgcn_s_setprio(1);
        #pragma unroll
        for (int nd = 0; nd < 4; ++nd)
          acc[nd] = __builtin_amdgcn_mfma_f32_16x16x32_bf16(vf[nd], pa.v, acc[nd], 0, 0, 0);
        __builtin_amdgcn_s_setprio(0);
      }
    }
    if (lt + 1 < ntl) {
      // counted barrier: my t+1 loads done; t+2 loads (if any) stay in flight
      if (pre2) tile_barrier_keep2();
      else      tile_barrier_keep0();
    }
    cur = (cur + 1 == 3) ? 0 : cur + 1;
  }

  // ---- epilogue: reduce l over the 4 g-lanes sharing q=c; write partials
  float lsum = lstate;
  lsum += __shfl_xor(lsum, 16);
  lsum += __shfl_xor(lsum, 32);
  const int qrow = w * 16 + c;                     // 0..127 within q-tile
  #pragma unroll
  for (int nd = 0; nd < 4; ++nd) {
    ushort4 o4;
    o4.x = f2b(acc[nd][0]); o4.y = f2b(acc[nd][1]);
    o4.z = f2b(acc[nd][2]); o4.w = f2b(acc[nd][3]);
    *(ushort4*)(partO + (size_t)bid * 8192 + qrow * 64 + nd * 16 + 4 * g) = o4;
  }
  if (g == 0) {
    partML[(size_t)bid * 256 + qrow * 2 + 0] = mstate;
    partML[(size_t)bid * 256 + qrow * 2 + 1] = lsum;
  }
}

// ---------------- combine: merge <=4 KV-chunk partials per 128-row q-tile ----
__global__ __launch_bounds__(256) void attn_combine(const unsigned short* __restrict__ partO,
                                                    const float* __restrict__ partML,
                                                    unsigned short* __restrict__ out) {
  const int bid = blockIdx.x;                      // 512 = 16 qt x 32 bh
  const int qt = bid >> 5, bh = bid & 31;
  const int b = bh >> 4, h = bh & 15;
  const int np = (2 * qt + 9) >> 3;                // ceil((2qt+2)/8)
  const int base = (qt < 4) ? qt
                 : (qt < 8) ? 4 + 2 * (qt - 4)
                 : (qt < 12) ? 12 + 3 * (qt - 8)
                 : 24 + 4 * (qt - 12);
  const int t = threadIdx.x;
  const int row = t >> 1, cg = (t & 1) * 32;       // 128 rows x 2 col-halves of 32
  const float SCL = 0.18033688f;
  // attn dispatches chunk cid_work at raw bid-chunk (39 - cid_work)
  float mstar = -1e30f;
  #pragma unroll
  for (int p = 0; p < 4; ++p)
    if (p < np)
      mstar = fmaxf(mstar, partML[(size_t)(((39 - (base + p)) << 5) | bh) * 256 + row * 2]);
  float L = 0.f;
  float o[32];
  #pragma unroll
  for (int j = 0; j < 32; ++j) o[j] = 0.f;
  #pragma unroll
  for (int p = 0; p < 4; ++p) {
    if (p < np) {
      int slot = ((39 - (base + p)) << 5) | bh;
      float mp = partML[(size_t)slot * 256 + row * 2 + 0];
      float lp = partML[(size_t)slot * 256 + row * 2 + 1];
      float wgt = exp2f((mp - mstar) * SCL);
      L = fmaf(wgt, lp, L);
      const unsigned short* src = partO + (size_t)slot * 8192 + row * 64 + cg;
      #pragma unroll
      for (int q = 0; q < 4; ++q) {
        u16x8 a = *(const u16x8*)(src + q * 8);
        #pragma unroll
        for (int j = 0; j < 8; ++j)
          o[q * 8 + j] = fmaf(b2f(a[j]), wgt, o[q * 8 + j]);
      }
    }
  }
  float rinv = 1.0f / L;
  size_t trow = (size_t)b * 2048 + qt * 128 + row;
  #pragma unroll
  for (int q = 0; q < 4; ++q) {
    u16x8 r;
    #pragma unroll
    for (int j = 0; j < 8; ++j) r[j] = f2b(o[q * 8 + j] * rinv);
    *(u16x8*)(out + trow * 1024 + h * 64 + cg + q * 8) = r;
  }
}

// ---------------- launch ----------------
extern "C" void kernel_launch(void* const* d_in, const int* in_sizes, int n_in,
                              void* d_out, int out_size, void* d_ws, size_t ws_size,
                              hipStream_t stream) {
  const float* x      = (const float*)d_in[0];
  const float* W_attn = (const float*)d_in[1];
  const float* b_attn = (const float*)d_in[2];
  const float* W_proj = (const float*)d_in[3];
  const float* b_proj = (const float*)d_in[4];
  float* out = (float*)d_out;

  char* ws = (char*)d_ws;
  unsigned short* Wproj_t  = (unsigned short*)(ws + 0);
  unsigned short* qk       = (unsigned short*)(ws + 2097152);
  unsigned short* vT       = (unsigned short*)(ws + 18874368);
  unsigned short* x_bf     = (unsigned short*)(ws + 27262976);
  unsigned short* Wattn_t  = (unsigned short*)(ws + 35651584);
  unsigned short* partO    = (unsigned short*)(ws + 27262976);
  unsigned short* attn_out = (unsigned short*)(ws + 48234496);
  float*          partML   = (float*)(ws + 56623104);

  convert_f32_bf16<<<2048, 256, 0, stream>>>(x, x_bf, 4194304);
  transpose_f32_bf16<<<dim3(96, 32), dim3(32, 8), 0, stream>>>(W_attn, Wattn_t, 1024, 3072);
  transpose_f32_bf16<<<dim3(32, 32), dim3(32, 8), 0, stream>>>(W_proj, Wproj_t, 1024, 1024);

  gemm_bt<true, true><<<dim3(32, 24), 512, 0, stream>>>(x_bf, Wattn_t, b_attn, qk, vT,
                                                        4096, 3072, 1024);
  attn_kernel<<<1280, 512, 0, stream>>>(qk, vT, partO, partML);
  attn_combine<<<512, 256, 0, stream>>>(partO, partML, attn_out);
  gemm_bt<false, false><<<dim3(32, 8), 512, 0, stream>>>(attn_out, Wproj_t, b_proj, out, nullptr,
                                                         4096, 1024, 1024);
}

// Round 16
// 134.722 us; speedup vs baseline: 1.0235x; 1.0235x over previous
//
#include <hip/hip_runtime.h>
#include <stdint.h>

typedef __attribute__((ext_vector_type(4))) float f32x4;
typedef __attribute__((ext_vector_type(8))) __bf16 bf16x8;
typedef __attribute__((ext_vector_type(8))) unsigned short u16x8;

__device__ __forceinline__ unsigned short f2b(float f) {
  unsigned u = __float_as_uint(f);
  u += 0x7FFFu + ((u >> 16) & 1u);   // RNE
  return (unsigned short)(u >> 16);
}
__device__ __forceinline__ float b2f(unsigned short s) {
  unsigned u = (unsigned)s << 16;
  return __uint_as_float(u);
}
__device__ __forceinline__ unsigned cvtpk_bf16(float lo, float hi) {
  unsigned r;
  asm("v_cvt_pk_bf16_f32 %0, %1, %2" : "=v"(r) : "v"(lo), "v"(hi));
  return r;
}

__device__ __forceinline__ void gload_lds16(const void* g, void* l) {
  typedef __attribute__((address_space(1))) void GV1;
  typedef __attribute__((address_space(3))) void LV3;
  __builtin_amdgcn_global_load_lds((GV1*)(void*)g, (LV3*)l, 16, 0, 0);
}

// counted-vmcnt tile barrier (T4): wait own oldest loads, keep newest N flying,
// then s_barrier. sched_barrier(0) fences against compiler hoisting (rule #18).
__device__ __forceinline__ void tile_barrier_keep4() {
  asm volatile("s_waitcnt vmcnt(4)" ::: "memory");
  __builtin_amdgcn_sched_barrier(0);
  __builtin_amdgcn_s_barrier();
  __builtin_amdgcn_sched_barrier(0);
}
__device__ __forceinline__ void tile_barrier_keep2() {
  asm volatile("s_waitcnt vmcnt(2)" ::: "memory");
  __builtin_amdgcn_sched_barrier(0);
  __builtin_amdgcn_s_barrier();
  __builtin_amdgcn_sched_barrier(0);
}
__device__ __forceinline__ void tile_barrier_keep0() {
  asm volatile("s_waitcnt vmcnt(0)" ::: "memory");
  __builtin_amdgcn_sched_barrier(0);
  __builtin_amdgcn_s_barrier();
  __builtin_amdgcn_sched_barrier(0);
}

// ---------------- conversion kernels ----------------
__global__ __launch_bounds__(256) void convert_f32_bf16(const float* __restrict__ in,
                                                        unsigned short* __restrict__ out, int n) {
  int i = (blockIdx.x * 256 + threadIdx.x) * 8;
  if (i >= n) return;
  float4 a = *(const float4*)(in + i);
  float4 b = *(const float4*)(in + i + 4);
  u16x8 r;
  r[0] = f2b(a.x); r[1] = f2b(a.y); r[2] = f2b(a.z); r[3] = f2b(a.w);
  r[4] = f2b(b.x); r[5] = f2b(b.y); r[6] = f2b(b.z); r[7] = f2b(b.w);
  *(u16x8*)(out + i) = r;
}

// W [K][N] f32 -> Wt [N][K] bf16
__global__ __launch_bounds__(256) void transpose_f32_bf16(const float* __restrict__ W,
                                                          unsigned short* __restrict__ Wt,
                                                          int K, int N) {
  __shared__ unsigned short tile[32][33];
  int n0 = blockIdx.x * 32, k0 = blockIdx.y * 32;
  int tx = threadIdx.x, ty = threadIdx.y;  // 32 x 8
  #pragma unroll
  for (int j = 0; j < 32; j += 8)
    tile[ty + j][tx] = f2b(W[(size_t)(k0 + ty + j) * N + n0 + tx]);
  __syncthreads();
  #pragma unroll
  for (int j = 0; j < 32; j += 8)
    Wt[(size_t)(n0 + ty + j) * K + k0 + tx] = tile[tx][ty + j];
}

// ---------------- GEMM: C[M][N] = A[M][K] * Bt[N][K]^T + bias ----------------
// R15: counted-vmcnt 3-STAGE pipeline (T4, attn-validated idiom): BK=32,
// 3 LDS buffers (48KB), 256 thr / 4 waves (2x2, acc 4x4). Each iter stages
// K-step t+2; barrier = {s_waitcnt vmcnt(4); s_barrier} — the newest 4 loads
// stay IN FLIGHT across every barrier (never drain to 0 in the main loop),
// giving each load ~2 compute phases of latency cover. 768 blocks = exactly
// 3/CU (zero tail). GEMM regime fits the mechanism: short compute phase
// (~16 MFMA/step), long load latency — unlike attn (compute-bound, R15 null).
template <bool OUT_BF16, bool VSPLIT>
__global__ __launch_bounds__(256) void gemm_bt(const unsigned short* __restrict__ A,
                                               const unsigned short* __restrict__ Bt,
                                               const float* __restrict__ bias,
                                               void* __restrict__ Cout,
                                               unsigned short* __restrict__ vT,
                                               int M, int N, int K) {
  __shared__ unsigned short SMEM[24576];           // 48KB: 3 x {A[128x32] | B[128x32]}
  const int m0 = blockIdx.x * 128, n0 = blockIdx.y * 128;
  const int tid = threadIdx.x;
  const int w = tid >> 6, l = tid & 63;
  const int wm = w >> 1, wn = w & 1;
  const int c = l & 15, g = l >> 4;
  const int NT = K >> 5;                           // BK=32 K-steps
  // staging: wave w covers rows w*32 + i*16 + (l>>2), chunk (l&3)*8 (16B/lane)
  const unsigned short* aptr[2];
  const unsigned short* bptr[2];
  #pragma unroll
  for (int i = 0; i < 2; ++i) {
    int rb = w * 32 + i * 16;
    aptr[i] = A  + (size_t)(m0 + rb + (l >> 2)) * K + (l & 3) * 8;
    bptr[i] = Bt + (size_t)(n0 + rb + (l >> 2)) * K + (l & 3) * 8;
  }
  f32x4 acc[4][4] = {};
  // ---- prologue: stage t0 -> buf0, t1 -> buf1 (deep prefetch)
  #pragma unroll
  for (int i = 0; i < 2; ++i) {
    int rb = w * 32 + i * 16;
    gload_lds16(aptr[i], &SMEM[rb * 32]);
    gload_lds16(bptr[i], &SMEM[4096 + rb * 32]);
  }
  if (NT > 1) {
    #pragma unroll
    for (int i = 0; i < 2; ++i) {
      int rb = w * 32 + i * 16;
      gload_lds16(aptr[i] + 32, &SMEM[8192 + rb * 32]);
      gload_lds16(bptr[i] + 32, &SMEM[8192 + 4096 + rb * 32]);
    }
    tile_barrier_keep4();                          // t0 done; t1's 4 still flying
  } else {
    tile_barrier_keep0();
  }
  int cur = 0;
  for (int t = 0; t < NT; ++t) {
    const bool pre2 = (t + 2 < NT);
    if (pre2) {  // stage K-step t+2 into the buffer freed at the last barrier
      int sb = cur + 2; if (sb >= 3) sb -= 3;
      #pragma unroll
      for (int i = 0; i < 2; ++i) {
        int rb = w * 32 + i * 16;
        gload_lds16(aptr[i] + (size_t)(t + 2) * 32, &SMEM[sb * 8192 + rb * 32]);
        gload_lds16(bptr[i] + (size_t)(t + 2) * 32, &SMEM[sb * 8192 + 4096 + rb * 32]);
      }
    }
    const unsigned short* Ab = &SMEM[cur * 8192];
    const unsigned short* Bb = &SMEM[cur * 8192 + 4096];
    bf16x8 af[4], bf[4];
    #pragma unroll
    for (int mi = 0; mi < 4; ++mi)
      af[mi] = *(const bf16x8*)&Ab[(wm * 64 + mi * 16 + c) * 32 + g * 8];
    #pragma unroll
    for (int ni = 0; ni < 4; ++ni)
      bf[ni] = *(const bf16x8*)&Bb[(wn * 64 + ni * 16 + c) * 32 + g * 8];
    __builtin_amdgcn_s_setprio(1);
    #pragma unroll
    for (int mi = 0; mi < 4; ++mi)
      #pragma unroll
      for (int ni = 0; ni < 4; ++ni)
        acc[mi][ni] = __builtin_amdgcn_mfma_f32_16x16x32_bf16(af[mi], bf[ni], acc[mi][ni], 0, 0, 0);
    __builtin_amdgcn_s_setprio(0);
    if (t + 1 < NT) {
      if (pre2) tile_barrier_keep4();              // t+1 done; t+2 stays flying
      else      tile_barrier_keep0();
    }
    cur = (cur + 1 == 3) ? 0 : cur + 1;
  }
  if (VSPLIT && n0 >= 2048) {
    // ---- V block: transpose via LDS (dead staging buffer), coalesced vT write
    __syncthreads();                               // all waves past last LDS read
    unsigned short* TR = SMEM;                     // [128 cols][136]
    #pragma unroll
    for (int mi = 0; mi < 4; ++mi)
      #pragma unroll
      for (int ni = 0; ni < 4; ++ni) {
        int cl = wn * 64 + ni * 16 + c;
        float bv = bias[n0 + cl];
        int rlb = wm * 64 + mi * 16 + 4 * g;
        ushort4 o4;
        o4.x = f2b(acc[mi][ni][0] + bv); o4.y = f2b(acc[mi][ni][1] + bv);
        o4.z = f2b(acc[mi][ni][2] + bv); o4.w = f2b(acc[mi][ni][3] + bv);
        *(ushort4*)&TR[cl * 136 + rlb] = o4;
      }
    __syncthreads();
    const int d0 = n0 - 2048;
    #pragma unroll
    for (int p = 0; p < 8; ++p) {
      int rowl = p * 16 + (tid >> 4);
      *(u16x8*)(vT + (size_t)(d0 + rowl) * 4096 + m0 + (tid & 15) * 8) =
          *(const u16x8*)&TR[rowl * 136 + (tid & 15) * 8];
    }
    return;
  }
  const int NS = VSPLIT ? 2048 : N;                // qk buffer stride for VSPLIT
  #pragma unroll
  for (int mi = 0; mi < 4; ++mi) {
    #pragma unroll
    for (int ni = 0; ni < 4; ++ni) {
      int colg = n0 + wn * 64 + ni * 16 + c;
      float bv = bias[colg];
      #pragma unroll
      for (int r = 0; r < 4; ++r) {
        int rowg = m0 + wm * 64 + mi * 16 + 4 * g + r;
        float v = acc[mi][ni][r] + bv;
        if (OUT_BF16)
          ((unsigned short*)Cout)[(size_t)rowg * NS + colg] = f2b(v);
        else
          ((float*)Cout)[(size_t)rowg * NS + colg] = v;
      }
    }
  }
}

// ---------------- causal flash attention, SPLIT-KV + SWAPPED MFMA, QBLK=128 ----
// (unchanged from R15 — at its ~61us structural floor; counted-vmcnt kept)
__global__ __launch_bounds__(512) void attn_kernel(const unsigned short* __restrict__ qk,
                                                   const unsigned short* __restrict__ vT,
                                                   unsigned short* __restrict__ partO,
                                                   float* __restrict__ partML) {
  __shared__ unsigned short K_lds[3][64 * 64];     // [buf][kv][d], XOR-swizzled rows
  __shared__ unsigned short V_lds[3][64 * 64];     // [buf] V^T [d][kv], XOR-swizzled rows
  const int bid = blockIdx.x;
  const int bh = bid & 31;
  const int cid = 39 - (bid >> 5);                 // heavy-first
  int qt, ct;
  if (cid < 4)       { qt = cid;            ct = 0; }
  else if (cid < 12) { int e = cid - 4;  qt = 4 + (e >> 1);  ct = e & 1; }
  else if (cid < 24) { int e = cid - 12; int q3 = e / 3; qt = 8 + q3; ct = e - 3 * q3; }
  else               { int e = cid - 24; qt = 12 + (e >> 2); ct = e & 3; }
  const int ntt = 2 * qt + 2;                      // total kv tiles for this q-tile
  const int t0 = ct * 8;
  const int ntl = min(ntt - t0, 8);                // tiles in this chunk (1..8)
  const int b = bh >> 4, h = bh & 15;
  const int tid = threadIdx.x, w = tid >> 6, l = tid & 63;
  const int c = l & 15, g = l >> 4;
  const int hi = g >> 1;
  const int srcA = c + ((g & 1) << 5);             // bpermute pattern A (j=0,1)
  const int srcB = srcA + 16;                      // pattern B (j=2,3)
  const size_t row0 = (size_t)b * 2048;
  const float SCL = 0.18033688f;                   // 0.125 * log2(e)
  const int KSTRIDE = 64 * 2048;                   // qk elems per kv-tile step
  const int VSTRIDE = 64;                          // vT elems per kv-tile step

  const int q0w = qt * 128 + w * 16;
  const int qg = q0w + c;                          // this lane's q row (global)

  // Q fragments (B operand of swapped QK^T) — issued first (oldest in vmcnt)
  bf16x8 qf[2];
  #pragma unroll
  for (int ks = 0; ks < 2; ++ks)
    qf[ks] = *(const bf16x8*)(qk + (row0 + qg) * 2048 + h * 64 + ks * 32 + g * 8);

  f32x4 acc[4] = {};                               // O^T: acc[nd][r] = O[q=c][d=16nd+4g+r]
  float mstate = -1e30f, lstate = 0.f;

  // ---- hoisted per-lane global pointers (advance per tile)
  const int krow = w * 8 + (l >> 3);               // lane's row in tile (K: kv; V: d)
  const int kch = (l & 7) ^ (krow & 7);            // pre-swizzled source chunk (m173)
  const unsigned short* kptr = qk + (row0 + t0 * 64 + krow) * 2048 + 1024 + h * 64 + kch * 8;
  const unsigned short* vptr = vT + (size_t)(h * 64 + krow) * 4096 + (b * 2048 + t0 * 64) + kch * 8;
  const int kdst = (w * 8) * 64;                   // wave-uniform LDS base (elems)

  // ---- prologue: stage t0 -> buf0, t1 -> buf1 (deep prefetch)
  gload_lds16(kptr, &K_lds[0][kdst]);
  gload_lds16(vptr, &V_lds[0][kdst]);
  if (ntl > 1) {
    gload_lds16(kptr + KSTRIDE, &K_lds[1][kdst]);
    gload_lds16(vptr + VSTRIDE, &V_lds[1][kdst]);
    tile_barrier_keep2();                          // Q + t0 done; t1 still flying
  } else {
    tile_barrier_keep0();
  }

  int cur = 0;
  for (int lt = 0; lt < ntl; ++lt) {
    const int kv0 = (t0 + lt) * 64;
    const bool pre2 = (lt + 2 < ntl);
    if (pre2) {  // stage tile t+2 into the buffer freed at the last barrier
      int sb = cur + 2; if (sb >= 3) sb -= 3;
      gload_lds16(kptr + 2 * KSTRIDE, &K_lds[sb][kdst]);
      gload_lds16(vptr + 2 * VSTRIDE, &V_lds[sb][kdst]);
    }
    kptr += KSTRIDE;
    vptr += VSTRIDE;
    if (kv0 <= q0w + 15) {  // wave-uniform: skip tiles fully above the diagonal
      const char* Kb = (const char*)K_lds[cur];
      const char* Vb = (const char*)V_lds[cur];
      // ---- S^T = mfma(K, Q): s[nk][r] = S[q=qg][kv = kv0 + 16nk + 4g + r]
      f32x4 s[4] = {};
      #pragma unroll
      for (int ks = 0; ks < 2; ++ks) {
        bf16x8 kf[4];
        #pragma unroll
        for (int nk = 0; nk < 4; ++nk) {
          int row = nk * 16 + c;
          kf[nk] = *(const bf16x8*)(Kb + row * 128 + ((ks * 64 + g * 16) ^ ((row & 7) << 4)));
        }
        __builtin_amdgcn_s_setprio(1);
        #pragma unroll
        for (int nk = 0; nk < 4; ++nk)
          s[nk] = __builtin_amdgcn_mfma_f32_16x16x32_bf16(kf[nk], qf[ks], s[nk], 0, 0, 0);
        __builtin_amdgcn_s_setprio(0);
      }
      // ---- causal mask on any tile straddling this wave's rows (wave-uniform)
      if (kv0 + 63 > q0w) {
        #pragma unroll
        for (int nk = 0; nk < 4; ++nk)
          #pragma unroll
          for (int r = 0; r < 4; ++r) {
            int kvg = kv0 + nk * 16 + 4 * g + r;
            if (kvg > qg) s[nk][r] = -1e30f;
          }
      }
      // ---- row max: in-lane tree + 2 shfls (lanes c,c+16,c+32,c+48 share q)
      float a0 = fmaxf(fmaxf(s[0][0], s[0][1]), fmaxf(s[0][2], s[0][3]));
      float a1 = fmaxf(fmaxf(s[1][0], s[1][1]), fmaxf(s[1][2], s[1][3]));
      float a2 = fmaxf(fmaxf(s[2][0], s[2][1]), fmaxf(s[2][2], s[2][3]));
      float a3 = fmaxf(fmaxf(s[3][0], s[3][1]), fmaxf(s[3][2], s[3][3]));
      float mx = fmaxf(fmaxf(a0, a1), fmaxf(a2, a3));
      mx = fmaxf(mx, __shfl_xor(mx, 16));
      mx = fmaxf(mx, __shfl_xor(mx, 32));
      // ---- alpha==1 fast path (wave-uniform); rescale lane-local
      if (!__all(mx <= mstate)) {
        float mnew = fmaxf(mstate, mx);
        float alpha = exp2f((mstate - mnew) * SCL);
        mstate = mnew;
        lstate *= alpha;
        #pragma unroll
        for (int nd = 0; nd < 4; ++nd) acc[nd] *= alpha;
      }
      // ---- P = exp2(s*SCL - m*SCL), per-lane l partial
      float ms = mstate * SCL;
      #pragma unroll
      for (int nk = 0; nk < 4; ++nk) {
        #pragma unroll
        for (int r = 0; r < 4; ++r) s[nk][r] = exp2f(fmaf(s[nk][r], SCL, -ms));
        lstate += (s[nk][0] + s[nk][1]) + (s[nk][2] + s[nk][3]);
      }
      // ---- pack P to bf16 pairs
      unsigned pk[4][2];
      #pragma unroll
      for (int nk = 0; nk < 4; ++nk) {
        pk[nk][0] = cvtpk_bf16(s[nk][0], s[nk][1]);
        pk[nk][1] = cvtpk_bf16(s[nk][2], s[nk][3]);
      }
      // ---- O^T += mfma(V^T, P^T): B-frag pa[vks] = P[q=c][kv=32vks+8g+e]
      #pragma unroll
      for (int vks = 0; vks < 2; ++vks) {
        unsigned rA00 = __shfl(pk[2 * vks][0], srcA, 64);
        unsigned rA01 = __shfl(pk[2 * vks][1], srcA, 64);
        unsigned rA10 = __shfl(pk[2 * vks + 1][0], srcA, 64);
        unsigned rA11 = __shfl(pk[2 * vks + 1][1], srcA, 64);
        unsigned rB00 = __shfl(pk[2 * vks][0], srcB, 64);
        unsigned rB01 = __shfl(pk[2 * vks][1], srcB, 64);
        unsigned rB10 = __shfl(pk[2 * vks + 1][0], srcB, 64);
        unsigned rB11 = __shfl(pk[2 * vks + 1][1], srcB, 64);
        union { unsigned u[4]; bf16x8 v; } pa;
        pa.u[0] = hi ? rA10 : rA00;
        pa.u[1] = hi ? rA11 : rA01;
        pa.u[2] = hi ? rB10 : rB00;
        pa.u[3] = hi ? rB11 : rB01;
        bf16x8 vf[4];
        #pragma unroll
        for (int nd = 0; nd < 4; ++nd) {
          int row = nd * 16 + c;
          vf[nd] = *(const bf16x8*)(Vb + row * 128 + ((vks * 64 + g * 16) ^ ((row & 7) << 4)));
        }
        __builtin_amdgcn_s_setprio(1);
        #pragma unroll
        for (int nd = 0; nd < 4; ++nd)
          acc[nd] = __builtin_amdgcn_mfma_f32_16x16x32_bf16(vf[nd], pa.v, acc[nd], 0, 0, 0);
        __builtin_amdgcn_s_setprio(0);
      }
    }
    if (lt + 1 < ntl) {
      if (pre2) tile_barrier_keep2();
      else      tile_barrier_keep0();
    }
    cur = (cur + 1 == 3) ? 0 : cur + 1;
  }

  // ---- epilogue: reduce l over the 4 g-lanes sharing q=c; write partials
  float lsum = lstate;
  lsum += __shfl_xor(lsum, 16);
  lsum += __shfl_xor(lsum, 32);
  const int qrow = w * 16 + c;                     // 0..127 within q-tile
  #pragma unroll
  for (int nd = 0; nd < 4; ++nd) {
    ushort4 o4;
    o4.x = f2b(acc[nd][0]); o4.y = f2b(acc[nd][1]);
    o4.z = f2b(acc[nd][2]); o4.w = f2b(acc[nd][3]);
    *(ushort4*)(partO + (size_t)bid * 8192 + qrow * 64 + nd * 16 + 4 * g) = o4;
  }
  if (g == 0) {
    partML[(size_t)bid * 256 + qrow * 2 + 0] = mstate;
    partML[(size_t)bid * 256 + qrow * 2 + 1] = lsum;
  }
}

// ---------------- combine: merge <=4 KV-chunk partials per 128-row q-tile ----
__global__ __launch_bounds__(256) void attn_combine(const unsigned short* __restrict__ partO,
                                                    const float* __restrict__ partML,
                                                    unsigned short* __restrict__ out) {
  const int bid = blockIdx.x;                      // 512 = 16 qt x 32 bh
  const int qt = bid >> 5, bh = bid & 31;
  const int b = bh >> 4, h = bh & 15;
  const int np = (2 * qt + 9) >> 3;                // ceil((2qt+2)/8)
  const int base = (qt < 4) ? qt
                 : (qt < 8) ? 4 + 2 * (qt - 4)
                 : (qt < 12) ? 12 + 3 * (qt - 8)
                 : 24 + 4 * (qt - 12);
  const int t = threadIdx.x;
  const int row = t >> 1, cg = (t & 1) * 32;       // 128 rows x 2 col-halves of 32
  const float SCL = 0.18033688f;
  // attn dispatches chunk cid_work at raw bid-chunk (39 - cid_work)
  float mstar = -1e30f;
  #pragma unroll
  for (int p = 0; p < 4; ++p)
    if (p < np)
      mstar = fmaxf(mstar, partML[(size_t)(((39 - (base + p)) << 5) | bh) * 256 + row * 2]);
  float L = 0.f;
  float o[32];
  #pragma unroll
  for (int j = 0; j < 32; ++j) o[j] = 0.f;
  #pragma unroll
  for (int p = 0; p < 4; ++p) {
    if (p < np) {
      int slot = ((39 - (base + p)) << 5) | bh;
      float mp = partML[(size_t)slot * 256 + row * 2 + 0];
      float lp = partML[(size_t)slot * 256 + row * 2 + 1];
      float wgt = exp2f((mp - mstar) * SCL);
      L = fmaf(wgt, lp, L);
      const unsigned short* src = partO + (size_t)slot * 8192 + row * 64 + cg;
      #pragma unroll
      for (int q = 0; q < 4; ++q) {
        u16x8 a = *(const u16x8*)(src + q * 8);
        #pragma unroll
        for (int j = 0; j < 8; ++j)
          o[q * 8 + j] = fmaf(b2f(a[j]), wgt, o[q * 8 + j]);
      }
    }
  }
  float rinv = 1.0f / L;
  size_t trow = (size_t)b * 2048 + qt * 128 + row;
  #pragma unroll
  for (int q = 0; q < 4; ++q) {
    u16x8 r;
    #pragma unroll
    for (int j = 0; j < 8; ++j) r[j] = f2b(o[q * 8 + j] * rinv);
    *(u16x8*)(out + trow * 1024 + h * 64 + cg + q * 8) = r;
  }
}

// ---------------- launch ----------------
extern "C" void kernel_launch(void* const* d_in, const int* in_sizes, int n_in,
                              void* d_out, int out_size, void* d_ws, size_t ws_size,
                              hipStream_t stream) {
  const float* x      = (const float*)d_in[0];
  const float* W_attn = (const float*)d_in[1];
  const float* b_attn = (const float*)d_in[2];
  const float* W_proj = (const float*)d_in[3];
  const float* b_proj = (const float*)d_in[4];
  float* out = (float*)d_out;

  char* ws = (char*)d_ws;
  unsigned short* Wproj_t  = (unsigned short*)(ws + 0);
  unsigned short* qk       = (unsigned short*)(ws + 2097152);
  unsigned short* vT       = (unsigned short*)(ws + 18874368);
  unsigned short* x_bf     = (unsigned short*)(ws + 27262976);
  unsigned short* Wattn_t  = (unsigned short*)(ws + 35651584);
  unsigned short* partO    = (unsigned short*)(ws + 27262976);
  unsigned short* attn_out = (unsigned short*)(ws + 48234496);
  float*          partML   = (float*)(ws + 56623104);

  convert_f32_bf16<<<2048, 256, 0, stream>>>(x, x_bf, 4194304);
  transpose_f32_bf16<<<dim3(96, 32), dim3(32, 8), 0, stream>>>(W_attn, Wattn_t, 1024, 3072);
  transpose_f32_bf16<<<dim3(32, 32), dim3(32, 8), 0, stream>>>(W_proj, Wproj_t, 1024, 1024);

  gemm_bt<true, true><<<dim3(32, 24), 256, 0, stream>>>(x_bf, Wattn_t, b_attn, qk, vT,
                                                        4096, 3072, 1024);
  attn_kernel<<<1280, 512, 0, stream>>>(qk, vT, partO, partML);
  attn_combine<<<512, 256, 0, stream>>>(partO, partML, attn_out);
  gemm_bt<false, false><<<dim3(32, 8), 256, 0, stream>>>(attn_out, Wproj_t, b_proj, out, nullptr,
                                                         4096, 1024, 1024);
}